// Round 4
// baseline (206.611 us; speedup 1.0000x reference)
//
#include <hip/hip_runtime.h>

// Y = X @ Q where Q is a 512x512 permutation (one-hot) matrix.
// Equivalent to a column gather: Y[n][j] = X[n][map[j]], map[j] = argmax_d Q[d][j].
//
// Memory-bound: 1.074 GB HBM traffic, roofline ~171 us @ 6.29 TB/s measured ceiling.
// This version: persistent blocks, double-buffered LDS, global_load_lds staging
// so tile t+1's HBM loads overlap tile t's gather+store (one barrier per tile).

#define DCOLS 512
#define TROWS 16                       // rows per tile
#define THREADS 512
#define TPB 8                          // tiles per block
#define TILE_ELEMS (TROWS * DCOLS)     // 8192 floats = 32 KiB

typedef float f32x4 __attribute__((ext_vector_type(4)));
typedef int   i32x4 __attribute__((ext_vector_type(4)));

typedef __attribute__((address_space(1))) const void g_void;
typedef __attribute__((address_space(3))) void lds_void;

__global__ __launch_bounds__(256)
void build_map_kernel(const float* __restrict__ Q, int* __restrict__ map) {
    int idx = blockIdx.x * 256 + threadIdx.x;   // idx = d*512 + j
    if (idx < DCOLS * DCOLS) {
        if (Q[idx] > 0.5f) {
            map[idx & (DCOLS - 1)] = idx >> 9;  // map[j] = d
        }
    }
}

__global__ __launch_bounds__(THREADS)
void permute_gather_kernel(const float* __restrict__ X,
                           const int* __restrict__ map,
                           float* __restrict__ out) {
    __shared__ float lds[2][TILE_ELEMS];   // 64 KiB -> 2 blocks/CU

    const int t  = threadIdx.x;
    const int jg = t & 127;    // float4 column-group within a row
    const int q  = t >> 7;     // 0..3: row within each quad
    const i32x4 m = ((const i32x4*)map)[jg];   // loaded once per block

    const long long tile0 = (long long)blockIdx.x * TPB;

    // Stage one 32 KiB tile directly into LDS (linear, wave-uniform-base +
    // lane*16 layout — exactly what global_load_lds requires).
    auto stage = [&](int buf, long long tile) {
        const float* src = X + tile * TILE_ELEMS;
        #pragma unroll
        for (int i = 0; i < 4; ++i) {
            const int off = (t + i * THREADS) * 4;   // float index, 16B per thread
            __builtin_amdgcn_global_load_lds((g_void*)(src + off),
                                             (lds_void*)&lds[buf][off],
                                             16, 0, 0);
        }
    };

    stage(0, tile0);
    __syncthreads();   // compiler drains vmcnt(0) before barrier -> buf0 ready

    int cur = 0;
    #pragma unroll
    for (int it = 0; it < TPB; ++it) {
        // Prefetch next tile into the other buffer (overlaps gather below).
        if (it + 1 < TPB) stage(cur ^ 1, tile0 + it + 1);

        // Gather tile `it` from LDS, coalesced nontemporal float4 stores.
        const long long n0 = (tile0 + it) * TROWS;
        float* orow = out + n0 * DCOLS;
        #pragma unroll
        for (int rp = 0; rp < TROWS / 4; ++rp) {
            const int row = rp * 4 + q;
            f32x4 o;
            o.x = lds[cur][row * DCOLS + m.x];
            o.y = lds[cur][row * DCOLS + m.y];
            o.z = lds[cur][row * DCOLS + m.z];
            o.w = lds[cur][row * DCOLS + m.w];
            __builtin_nontemporal_store(o, (f32x4*)(orow + row * DCOLS) + jg);
        }

        // One barrier per tile: everyone done reading lds[cur], and the
        // vmcnt(0) drain guarantees lds[cur^1]'s loads have landed.
        __syncthreads();
        cur ^= 1;
    }
}

extern "C" void kernel_launch(void* const* d_in, const int* in_sizes, int n_in,
                              void* d_out, int out_size, void* d_ws, size_t ws_size,
                              hipStream_t stream) {
    const float* X = (const float*)d_in[0];
    const float* Q = (const float*)d_in[1];
    float* out = (float*)d_out;
    int* map = (int*)d_ws;   // 512 ints = 2 KiB scratch

    const int N = in_sizes[0] / DCOLS;          // 262144
    const int ntiles = N / TROWS;               // 16384
    const int nblocks = ntiles / TPB;           // 2048

    build_map_kernel<<<(DCOLS * DCOLS + 255) / 256, 256, 0, stream>>>(Q, map);
    permute_gather_kernel<<<nblocks, THREADS, 0, stream>>>(X, map, out);
}

// Round 5
// 206.435 us; speedup vs baseline: 1.0009x; 1.0009x over previous
//
#include <hip/hip_runtime.h>

// Y = X @ Q where Q is a 512x512 permutation (one-hot) matrix.
// Equivalent to a column gather: Y[n][j] = X[n][map[j]], map[j] = argmax_d Q[d][j].
//
// Memory-bound: 1.074 GB HBM traffic, roofline ~171 us @ 6.29 TB/s measured ceiling.
// This version: BARRIER-FREE. Each wave autonomously stages one 2 KiB row into a
// wave-private LDS slab (producer == consumer, so no __syncthreads is ever needed),
// register-double-buffers the next row's loads under the current row's gather, and
// writes coalesced nontemporal float4 stores. 16 KiB LDS / 256 thr -> 8 blocks/CU
// (32 waves/CU), grid sized to exactly fill the chip one-shot.

#define DCOLS 512
#define ROWS_PER_WAVE 32
#define THREADS 256
#define WAVES_PER_BLOCK (THREADS / 64)

typedef float f32x4 __attribute__((ext_vector_type(4)));
typedef int   i32x4 __attribute__((ext_vector_type(4)));

__global__ __launch_bounds__(256)
void build_map_kernel(const float* __restrict__ Q, int* __restrict__ map) {
    int idx = blockIdx.x * 256 + threadIdx.x;   // idx = d*512 + j
    if (idx < DCOLS * DCOLS) {
        if (Q[idx] > 0.5f) {
            map[idx & (DCOLS - 1)] = idx >> 9;  // map[j] = d
        }
    }
}

__global__ __launch_bounds__(THREADS)
void permute_gather_kernel(const float* __restrict__ X,
                           const int* __restrict__ map,
                           float* __restrict__ out) {
    // Per-wave double slab: [wave][buf][row]. 4 * 2 * 2KiB = 16 KiB.
    __shared__ float lds[WAVES_PER_BLOCK][2][DCOLS];

    const int t  = threadIdx.x;
    const int wv = t >> 6;
    const int l  = t & 63;

    // Each lane stores output quads at cols [4l,4l+4) and [256+4l, 256+4l+4).
    const i32x4 m0 = ((const i32x4*)map)[l];
    const i32x4 m1 = ((const i32x4*)map)[l + 64];

    const long long r0 =
        ((long long)blockIdx.x * WAVES_PER_BLOCK + wv) * ROWS_PER_WAVE;

    float* slab[2] = { lds[wv][0], lds[wv][1] };

    // Prologue: stage row r0 into slab 0.
    {
        const f32x4* src = (const f32x4*)(X + r0 * DCOLS);
        f32x4 a0 = __builtin_nontemporal_load(&src[l]);
        f32x4 a1 = __builtin_nontemporal_load(&src[l + 64]);
        ((f32x4*)slab[0])[l]      = a0;
        ((f32x4*)slab[0])[l + 64] = a1;
    }

    // Steady state: gather row i from slab[i&1] while row i+1 streams into
    // registers, then lands in slab[(i+1)&1]. Same-wave producer/consumer:
    // the compiler's own vmcnt/lgkmcnt waits are the only synchronization.
    for (int i = 0; i < ROWS_PER_WAVE - 1; ++i) {
        const float* cur = slab[i & 1];
        float* nxt = slab[(i + 1) & 1];

        const f32x4* nsrc = (const f32x4*)(X + (r0 + i + 1) * DCOLS);
        f32x4 b0 = __builtin_nontemporal_load(&nsrc[l]);
        f32x4 b1 = __builtin_nontemporal_load(&nsrc[l + 64]);

        f32x4 o0, o1;
        o0.x = cur[m0.x]; o0.y = cur[m0.y]; o0.z = cur[m0.z]; o0.w = cur[m0.w];
        o1.x = cur[m1.x]; o1.y = cur[m1.y]; o1.z = cur[m1.z]; o1.w = cur[m1.w];
        f32x4* dst = (f32x4*)(out + (r0 + i) * DCOLS);
        __builtin_nontemporal_store(o0, &dst[l]);
        __builtin_nontemporal_store(o1, &dst[l + 64]);

        ((f32x4*)nxt)[l]      = b0;
        ((f32x4*)nxt)[l + 64] = b1;
    }

    // Epilogue: gather the last row.
    {
        const int i = ROWS_PER_WAVE - 1;
        const float* cur = slab[i & 1];
        f32x4 o0, o1;
        o0.x = cur[m0.x]; o0.y = cur[m0.y]; o0.z = cur[m0.z]; o0.w = cur[m0.w];
        o1.x = cur[m1.x]; o1.y = cur[m1.y]; o1.z = cur[m1.z]; o1.w = cur[m1.w];
        f32x4* dst = (f32x4*)(out + (r0 + i) * DCOLS);
        __builtin_nontemporal_store(o0, &dst[l]);
        __builtin_nontemporal_store(o1, &dst[l + 64]);
    }
}

extern "C" void kernel_launch(void* const* d_in, const int* in_sizes, int n_in,
                              void* d_out, int out_size, void* d_ws, size_t ws_size,
                              hipStream_t stream) {
    const float* X = (const float*)d_in[0];
    const float* Q = (const float*)d_in[1];
    float* out = (float*)d_out;
    int* map = (int*)d_ws;   // 512 ints = 2 KiB scratch

    const int N = in_sizes[0] / DCOLS;                      // 262144
    const int rows_per_block = WAVES_PER_BLOCK * ROWS_PER_WAVE;  // 128
    const int nblocks = N / rows_per_block;                 // 2048

    build_map_kernel<<<(DCOLS * DCOLS + 255) / 256, 256, 0, stream>>>(Q, map);
    permute_gather_kernel<<<nblocks, THREADS, 0, stream>>>(X, map, out);
}

// Round 7
// 190.684 us; speedup vs baseline: 1.0835x; 1.0826x over previous
//
#include <hip/hip_runtime.h>

// Y = X @ Q where Q is a 512x512 permutation (one-hot) matrix.
// Equivalent to a column gather: Y[n][j] = X[n][map[j]], map[j] = argmax_d Q[d][j].
//
// Memory-bound: 1.074 GB HBM traffic, roofline ~171 us @ 6.29 TB/s measured ceiling.
// This version: one-shot oversubscribed small blocks (32768, dynamic balancing)
// + global_load_lds direct HBM->LDS staging (no VGPR round-trip)
// + wave-autonomous (each wave stages/consumes its own 4 KiB slab; ZERO barriers).
// R6 bug fixed: global_load_lds needs a PER-LANE global source address
// (lane l reads 16B at src + l*16); R6 passed a wave-uniform src.

#define DCOLS 512
#define ROWS_PER_WAVE 2
#define THREADS 256
#define WAVES_PER_BLOCK (THREADS / 64)

typedef float f32x4 __attribute__((ext_vector_type(4)));
typedef int   i32x4 __attribute__((ext_vector_type(4)));

typedef __attribute__((address_space(1))) const void g_void;
typedef __attribute__((address_space(3))) void lds_void;

__global__ __launch_bounds__(256)
void build_map_kernel(const float* __restrict__ Q, int* __restrict__ map) {
    int idx = blockIdx.x * 256 + threadIdx.x;   // idx = d*512 + j
    if (idx < DCOLS * DCOLS) {
        if (Q[idx] > 0.5f) {
            map[idx & (DCOLS - 1)] = idx >> 9;  // map[j] = d
        }
    }
}

__global__ __launch_bounds__(THREADS)
void permute_gather_kernel(const float* __restrict__ X,
                           const int* __restrict__ map,
                           float* __restrict__ out) {
    // Per-wave slab: 2 rows = 4 KiB. Block total 16 KiB -> 8 blocks/CU (32 waves).
    __shared__ float lds[WAVES_PER_BLOCK][ROWS_PER_WAVE * DCOLS];

    const int t  = threadIdx.x;
    const int wv = t >> 6;
    const int l  = t & 63;

    // Lane l produces output col-quads [4l,4l+4) and [256+4l,256+4l+4) per row.
    const i32x4 m0 = ((const i32x4*)map)[l];
    const i32x4 m1 = ((const i32x4*)map)[l + 64];

    const long long n0 =
        ((long long)blockIdx.x * WAVES_PER_BLOCK + wv) * ROWS_PER_WAVE;

    // Stage this wave's 2 rows (4 KiB, contiguous in X) straight into LDS.
    // PER-LANE addresses on both sides: lane l handles 16B at offset l*16
    // within each 1 KiB chunk (64 lanes x 16B = 1 KiB per instruction).
    {
        const float* src = X + n0 * DCOLS + l * 4;   // per-lane global addr
        float* slab = lds[wv];
        #pragma unroll
        for (int i = 0; i < 4; ++i) {                // 4 x 1 KiB
            __builtin_amdgcn_global_load_lds((g_void*)(src + i * 256),
                                             (lds_void*)(slab + i * 256 + l * 4),
                                             16, 0, 0);
        }
    }

    // Same-wave producer/consumer: drain the async loads, then fence the
    // scheduler so nothing is hoisted above the drain (rule #18).
    asm volatile("s_waitcnt vmcnt(0)" ::: "memory");
    __builtin_amdgcn_sched_barrier(0);

    const float* slab = lds[wv];
    #pragma unroll
    for (int r = 0; r < ROWS_PER_WAVE; ++r) {
        const float* row = slab + r * DCOLS;
        f32x4 o0, o1;
        o0.x = row[m0.x]; o0.y = row[m0.y]; o0.z = row[m0.z]; o0.w = row[m0.w];
        o1.x = row[m1.x]; o1.y = row[m1.y]; o1.z = row[m1.z]; o1.w = row[m1.w];
        f32x4* dst = (f32x4*)(out + (n0 + r) * DCOLS);
        __builtin_nontemporal_store(o0, &dst[l]);
        __builtin_nontemporal_store(o1, &dst[l + 64]);
    }
}

extern "C" void kernel_launch(void* const* d_in, const int* in_sizes, int n_in,
                              void* d_out, int out_size, void* d_ws, size_t ws_size,
                              hipStream_t stream) {
    const float* X = (const float*)d_in[0];
    const float* Q = (const float*)d_in[1];
    float* out = (float*)d_out;
    int* map = (int*)d_ws;   // 512 ints = 2 KiB scratch

    const int N = in_sizes[0] / DCOLS;                               // 262144
    const int rows_per_block = WAVES_PER_BLOCK * ROWS_PER_WAVE;      // 8
    const int nblocks = N / rows_per_block;                          // 32768

    build_map_kernel<<<(DCOLS * DCOLS + 255) / 256, 256, 0, stream>>>(Q, map);
    permute_gather_kernel<<<nblocks, THREADS, 0, stream>>>(X, map, out);
}